// Round 9
// baseline (15635.516 us; speedup 1.0000x reference)
//
#include <hip/hip_runtime.h>
#include <hip/hip_fp16.h>

#define B_ 128
#define T_ 512
#define E_ 128
#define D_ 128
#define RLDS 143   // P rows resident in LDS (of 256 per block)

// exp2(C2*x) == e^(2x);  L2E = log2(e)
#define C2f 2.885390081777927f
#define L2E 1.4426950408889634f

__device__ __forceinline__ float rcpf_(float x){ return __builtin_amdgcn_rcpf(x); }
__device__ __forceinline__ float ex2_(float x){ return __builtin_amdgcn_exp2f(x); }

// LDS float atomic add — plain atomicAdd on __shared__ emits native ds_add_f32
__device__ __forceinline__ void lds_fadd(float* p, float v){
    atomicAdd(p, v);
}

// device-scope (cross-XCD coherent) data/flag helpers
__device__ __forceinline__ void gstoref(float* p, float v){
    __hip_atomic_store(p, v, __ATOMIC_RELAXED, __HIP_MEMORY_SCOPE_AGENT);
}
__device__ __forceinline__ float gloadf(const float* p){
    return __hip_atomic_load(p, __ATOMIC_RELAXED, __HIP_MEMORY_SCOPE_AGENT);
}
__device__ __forceinline__ void flag_set(int* p, int v){
    __hip_atomic_store(p, v, __ATOMIC_RELEASE, __HIP_MEMORY_SCOPE_AGENT);
}
__device__ __forceinline__ void flag_wait(int* p, int v){
    int it = 0;
    while (__hip_atomic_load(p, __ATOMIC_ACQUIRE, __HIP_MEMORY_SCOPE_AGENT) < v
           && it < (1 << 26)){ it++; __builtin_amdgcn_s_sleep(2); }
}

// out[n][k] = (half) in[k][n],  K x N input, 32x32 tiles, 256 threads.
__global__ __launch_bounds__(256) void transpose_half(const float* __restrict__ in,
                                                      __half* __restrict__ out,
                                                      int K, int N){
    __shared__ float tile[32][33];
    int n0 = blockIdx.x * 32, k0 = blockIdx.y * 32;
    int tx = threadIdx.x & 31, ty = threadIdx.x >> 5;
    #pragma unroll
    for (int i = ty; i < 32; i += 8)
        tile[i][tx] = in[(size_t)(k0 + i) * N + n0 + tx];
    __syncthreads();
    #pragma unroll
    for (int i = ty; i < 32; i += 8)
        out[(size_t)(n0 + i) * K + k0 + tx] = __float2half(tile[tx][i]);
}

// g[b][t] = sum_e enc[b][t][e] * Wc[1+e]   (fp32, loop-invariant y-dot basis)
__global__ __launch_bounds__(512) void g_kernel(const float* __restrict__ enc,
                                                const float* __restrict__ Wc,
                                                float* __restrict__ g){
    int b = blockIdx.x, t = threadIdx.x;
    const float4* ep = (const float4*)(enc + ((size_t)b * T_ + t) * E_);
    float acc = 0.f;
    #pragma unroll
    for (int i = 0; i < 32; i++){
        float4 ev = ep[i];
        acc = fmaf(ev.x, Wc[1 + 4*i + 0], acc);
        acc = fmaf(ev.y, Wc[1 + 4*i + 1], acc);
        acc = fmaf(ev.z, Wc[1 + 4*i + 2], acc);
        acc = fmaf(ev.w, Wc[1 + 4*i + 3], acc);
    }
    g[(size_t)b * T_ + t] = acc;
}

// P[b][n][t] = exp2(C2 * (sum_e enc[b][t][e]*Ua[e][n] + bu[n]))  as fp16
__global__ __launch_bounds__(256) void uenc_kernel(const float* __restrict__ enc,
                                                   const float* __restrict__ Ua,
                                                   const float* __restrict__ bu,
                                                   __half* __restrict__ P){
    int b = blockIdx.z;
    int t0 = blockIdx.x * 64;
    int n0 = blockIdx.y * 64;
    int tt = threadIdx.x & 63;
    int ng = threadIdx.x >> 6;
    const float* erow = enc + ((size_t)b * T_ + (t0 + tt)) * E_;
    const float* uap  = Ua + n0 + ng * 16;
    float acc[16];
    #pragma unroll
    for (int i = 0; i < 16; i++) acc[i] = 0.f;
    #pragma unroll 2
    for (int e0 = 0; e0 < E_; e0 += 4){
        float4 av = *(const float4*)(erow + e0);
        #pragma unroll
        for (int ee = 0; ee < 4; ee++){
            float a = (ee==0)?av.x:(ee==1)?av.y:(ee==2)?av.z:av.w;
            const float4* u4 = (const float4*)(uap + (size_t)(e0+ee) * T_);
            float4 x0 = u4[0], x1 = u4[1], x2 = u4[2], x3 = u4[3];
            acc[0]  = fmaf(a, x0.x, acc[0]);  acc[1]  = fmaf(a, x0.y, acc[1]);
            acc[2]  = fmaf(a, x0.z, acc[2]);  acc[3]  = fmaf(a, x0.w, acc[3]);
            acc[4]  = fmaf(a, x1.x, acc[4]);  acc[5]  = fmaf(a, x1.y, acc[5]);
            acc[6]  = fmaf(a, x1.z, acc[6]);  acc[7]  = fmaf(a, x1.w, acc[7]);
            acc[8]  = fmaf(a, x2.x, acc[8]);  acc[9]  = fmaf(a, x2.y, acc[9]);
            acc[10] = fmaf(a, x2.z, acc[10]); acc[11] = fmaf(a, x2.w, acc[11]);
            acc[12] = fmaf(a, x3.x, acc[12]); acc[13] = fmaf(a, x3.y, acc[13]);
            acc[14] = fmaf(a, x3.z, acc[14]); acc[15] = fmaf(a, x3.w, acc[15]);
        }
    }
    int nb = n0 + ng * 16;
    #pragma unroll
    for (int i = 0; i < 16; i++){
        float u = acc[i] + bu[nb + i];
        P[(size_t)b * T_ * T_ + (size_t)(nb + i) * T_ + t0 + tt] = __float2half(ex2_(C2f * u));
    }
}

__device__ __forceinline__ void dot8(float& acc, uint4 wv, float4 ha, float4 hb){
    float2 f0 = __half22float2(*reinterpret_cast<__half2*>(&wv.x));
    float2 f1 = __half22float2(*reinterpret_cast<__half2*>(&wv.y));
    float2 f2 = __half22float2(*reinterpret_cast<__half2*>(&wv.z));
    float2 f3 = __half22float2(*reinterpret_cast<__half2*>(&wv.w));
    acc = fmaf(ha.x, f0.x, acc); acc = fmaf(ha.y, f0.y, acc);
    acc = fmaf(ha.z, f1.x, acc); acc = fmaf(ha.w, f1.y, acc);
    acc = fmaf(hb.x, f2.x, acc); acc = fmaf(hb.y, f2.y, acc);
    acc = fmaf(hb.z, f3.x, acc); acc = fmaf(hb.w, f3.y, acc);
}

// 8 score-terms for one n-row: a_k += (-2Va[n]) / (P[n][t_k]*Q[n] + 1)
__device__ __forceinline__ void acc8(uint4 pv, float2 qv,
    float& a0, float& a1, float& a2, float& a3,
    float& a4, float& a5, float& a6, float& a7)
{
    float2 f0 = __half22float2(*reinterpret_cast<__half2*>(&pv.x));
    float2 f1 = __half22float2(*reinterpret_cast<__half2*>(&pv.y));
    float2 f2 = __half22float2(*reinterpret_cast<__half2*>(&pv.z));
    float2 f3 = __half22float2(*reinterpret_cast<__half2*>(&pv.w));
    float m;
    m = fmaf(f0.x, qv.x, 1.f); a0 = fmaf(rcpf_(m), qv.y, a0);
    m = fmaf(f0.y, qv.x, 1.f); a1 = fmaf(rcpf_(m), qv.y, a1);
    m = fmaf(f1.x, qv.x, 1.f); a2 = fmaf(rcpf_(m), qv.y, a2);
    m = fmaf(f1.y, qv.x, 1.f); a3 = fmaf(rcpf_(m), qv.y, a3);
    m = fmaf(f2.x, qv.x, 1.f); a4 = fmaf(rcpf_(m), qv.y, a4);
    m = fmaf(f2.y, qv.x, 1.f); a5 = fmaf(rcpf_(m), qv.y, a5);
    m = fmaf(f3.x, qv.x, 1.f); a6 = fmaf(rcpf_(m), qv.y, a6);
    m = fmaf(f3.y, qv.x, 1.f); a7 = fmaf(rcpf_(m), qv.y, a7);
}

// grid (128, 2): b = blockIdx.x, half-id h = blockIdx.y. 1024 threads.
// Round-7 verified structure (two pair-syncs, strided phase A, p.g algebra)
// with the reductions moved to native LDS float atomics:
//  - phase-A partials -> ds_add into spre/rzpre[256] (A-scratch deleted, 8 KB)
//  - phase-B partials -> ds_add into scoreacc[8][65]  (B-scratch deleted,
//    16 KB, 2 barriers); bias folded into the accumulator re-arm value
//  - freed LDS grows Plds 128 -> 143 rows (streamed P 128 -> 113 KB/step;
//    per-XCD stream 4.0 -> 3.6 MB, under the 4 MB L2 knife-edge)
//  - epilogue scratch aliased onto dead Plds (char pool)
__global__ __launch_bounds__(1024) void decoder_kernel(
    const float* __restrict__ enc,
    const float* __restrict__ labels,
    const float* __restrict__ init_h, const float* __restrict__ init_c,
    const float* __restrict__ Va,
    const float* __restrict__ ba, const float* __restrict__ bl,
    const float* __restrict__ Wc, const float* __restrict__ bc,
    const float* __restrict__ Wk,
    const float* __restrict__ W1, const float* __restrict__ b1,
    const float* __restrict__ W2, const float* __restrict__ b2,
    const __half* __restrict__ Wa_t, const __half* __restrict__ Wr_t,
    const __half* __restrict__ Pw, const float* __restrict__ gbuf,
    float* __restrict__ psbuf,
    int* __restrict__ fA, int* __restrict__ fB,
    float* __restrict__ out)
{
    __shared__ __align__(16) char pool_[RLDS * 1024]; // Plds (loop) / scratch (epilogue)
    __shared__ __align__(16) float hc_s[256];        // h [0,128), c [128,256)
    __shared__ __align__(16) float ctx_s[128];
    __shared__ __align__(16) float Q_s[256];         // e^{2 s[n]}, own half (local n)
    __shared__ __align__(16) float Vam_s[256];       // -2*Va[n], own half
    __shared__ __align__(16) float sc[512];          // half-score -> p[t]
    __shared__ __align__(16) float rz_s[512];        // h@Wr + bl (global m index)
    __shared__ __align__(16) float g_s[512];         // g[b][t]
    __shared__ __align__(16) float spre[256];        // s-partial accum (re-armed to ba)
    __shared__ __align__(16) float rzpre[256];       // rz-partial accum (re-armed to bl)
    __shared__ __align__(16) float scoreacc[8 * 65]; // half-score accum [k][q], bank-spread
    __shared__ __align__(16) float Wk_s[512];
    __shared__ float Wc_s[132];
    __shared__ float red[20];                        // 0-7 denom, 8-15 p.g

    const int tid = threadIdx.x;
    const int b = blockIdx.x;
    const int h_ = blockIdx.y;          // n-half / m-half id
    const int par_stride = B_ * 2;      // pair-slot layout

    float ba_reg = 0.f, bl_reg = 0.f;   // accumulator re-arm values

    if (tid < 128){
        hc_s[tid]       = init_h[b*128 + tid];
        hc_s[128 + tid] = init_c[b*128 + tid];
    }
    if (tid < 256){
        Vam_s[tid] = -2.f * Va[256*h_ + tid];
        ba_reg = ba[256*h_ + tid];
        spre[tid] = ba_reg;
    } else if (tid < 512){
        bl_reg = bl[256*h_ + tid - 256];
        rzpre[tid - 256] = bl_reg;
    }
    if (tid < 512){
        Wk_s[tid] = Wk[tid];
        g_s[tid]  = gbuf[(size_t)b * T_ + tid];
    }
    if (tid < 520) scoreacc[tid] = 0.f;
    if (tid < 129) Wc_s[tid] = Wc[tid];
    if (tid == 129) Wc_s[130] = bc[0];

    // block's n-half of P: rows n_loc in [0,256), global n = 256*h_ + n_loc
    const __half* Pb  = Pw + ((size_t)b * T_ + 256 * h_) * T_;
    const uint4*  Pb4 = (const uint4*)Pb;
    uint4* Plds4 = (uint4*)pool_;

    // Fill LDS rows 0..RLDS-1 directly (rows RLDS..255 stream each step)
    {
        int wid = tid >> 6, lane = tid & 63;
        for (int r = wid; r < RLDS; r += 16)
            Plds4[r * 64 + lane] = Pb4[(size_t)r * 64 + lane];
    }
    __syncthreads();

    int* myfA = &fA[b*2 + h_];   int* pfA = &fA[b*2 + (1 - h_)];
    int* myfB = &fB[b*2 + h_];   int* pfB = &fB[b*2 + (1 - h_)];

    const int np_ = tid & 255;   // phase-A row (local n or local m)
    const int kq_ = tid >> 8;    // phase-A k-quarter

    for (int t = 0; t < T_; t++){
        const int par = t & 1;
        float* psme = psbuf + ((size_t)par * par_stride + b*2 + h_)     * 768;
        float* pspr = psbuf + ((size_t)par * par_stride + b*2 + (1-h_)) * 768;

        // ---- phase A: s[n] own n-half (k/4) ; rz[m] own m-half (k/4)
        {
            const float4* hc4 = (const float4*)hc_s;
            float acc = 0.f, accr = 0.f;
            {   // s: 8 uint4 of Wa_t row (k in [kq_*64, kq_*64+64))
                const uint4* wa = (const uint4*)(Wa_t + (size_t)(256*h_ + np_) * 256 + kq_ * 64);
                #pragma unroll 4
                for (int i = 0; i < 8; i++){
                    uint4 wv = wa[i];
                    dot8(acc, wv, hc4[kq_*16 + 2*i], hc4[kq_*16 + 2*i + 1]);
                }
            }
            {   // rz: 4 uint4 of Wr_t row (k in [kq_*32, kq_*32+32))
                const uint4* wr = (const uint4*)(Wr_t + (size_t)(256*h_ + np_) * 128 + kq_ * 32);
                #pragma unroll
                for (int i = 0; i < 4; i++){
                    uint4 wv = wr[i];
                    dot8(accr, wv, hc4[kq_*8 + 2*i], hc4[kq_*8 + 2*i + 1]);
                }
            }
            lds_fadd(&spre[np_], acc);
            lds_fadd(&rzpre[np_], accr);
        }
        __syncthreads();
        // ---- A-reduce: read accumulators, re-arm with bias, produce Q / rz
        if (tid < 256){
            float s = spre[tid];
            spre[tid] = ba_reg;
            Q_s[tid] = ex2_(C2f * s);
        } else if (tid < 512){
            int m = tid - 256;
            float rzv = rzpre[m];
            rzpre[m] = bl_reg;
            rz_s[256*h_ + m] = rzv;
            gstoref(&psme[512 + m], rzv);   // publish own rz-half (flagA release)
        }
        __syncthreads();

        // ---- phase B: own 256 n-rows; first RLDS rows from LDS, rest streamed
        {
            int q = tid & 63, g = tid >> 6;
            int base = 16 * g;
            int nl = RLDS - base; nl = nl < 0 ? 0 : (nl > 16 ? 16 : nl);
            float a0=0.f,a1=0.f,a2=0.f,a3=0.f,a4=0.f,a5=0.f,a6=0.f,a7=0.f;
            const uint4* Pl = Plds4 + (size_t)base * 64 + q;
            #pragma unroll 4
            for (int j = 0; j < nl; j++){
                uint4 pv = Pl[j * 64];
                float2 qv = make_float2(Q_s[base + j], Vam_s[base + j]);
                acc8(pv, qv, a0,a1,a2,a3,a4,a5,a6,a7);
            }
            const uint4* Pg = Pb4 + (size_t)base * 64 + q;
            #pragma unroll 4
            for (int j = nl; j < 16; j++){
                uint4 pv = Pg[(size_t)j * 64];
                float2 qv = make_float2(Q_s[base + j], Vam_s[base + j]);
                acc8(pv, qv, a0,a1,a2,a3,a4,a5,a6,a7);
            }
            // accumulate half-scores: t = q*8 + k  ->  scoreacc[k*65 + q]
            lds_fadd(&scoreacc[0*65 + q], a0);
            lds_fadd(&scoreacc[1*65 + q], a1);
            lds_fadd(&scoreacc[2*65 + q], a2);
            lds_fadd(&scoreacc[3*65 + q], a3);
            lds_fadd(&scoreacc[4*65 + q], a4);
            lds_fadd(&scoreacc[5*65 + q], a5);
            lds_fadd(&scoreacc[6*65 + q], a6);
            lds_fadd(&scoreacc[7*65 + q], a7);
        }
        __syncthreads();
        // ---- B-final: gather half-score, zero accumulator, publish
        if (tid < 512){
            int qq = tid >> 3, kk = tid & 7;
            float v = scoreacc[kk*65 + qq];
            scoreacc[kk*65 + qq] = 0.f;
            sc[tid] = v;
            gstoref(&psme[tid], v);
        }
        __syncthreads();
        if (tid == 0){ flag_set(myfA, t + 1); flag_wait(pfA, t + 1); }
        __syncthreads();
        // ---- full score -> p; denom + p.g partials; pull partner rz-half
        if (tid < 512){
            float score = sc[tid] + gloadf(&pspr[tid]);
            float p = ex2_(score * L2E);
            sc[tid] = p;
            float ss = p;
            float sg = p * g_s[tid];
            #pragma unroll
            for (int off = 32; off; off >>= 1){
                ss += __shfl_xor(ss, off);
                sg += __shfl_xor(sg, off);
            }
            if ((tid & 63) == 0){ red[tid >> 6] = ss; red[8 + (tid >> 6)] = sg; }
        } else if (tid < 768){
            int m = tid - 512;
            rz_s[256*(1-h_) + m] = gloadf(&pspr[512 + m]);
        }
        __syncthreads();
        // ---- second pair-sync (pure pacing: preserves low-skew L2 equilibrium)
        if (tid == 0){ flag_set(myfB, t + 1); flag_wait(pfB, t + 1); }
        __syncthreads();

        // ---- phase D: y from (p.g)/denom; gates (Keras i,f,g,o); update h,c
        if (tid < 128){
            float dn = red[0]+red[1]+red[2]+red[3]+red[4]+red[5]+red[6]+red[7];
            float pg = red[8]+red[9]+red[10]+red[11]+red[12]+red[13]+red[14]+red[15];
            float lab = labels[(size_t)b * T_ + t];
            float y = fmaf(lab, Wc_s[0], pg * rcpf_(dn) + Wc_s[130]);
            float zi = rz_s[tid]       + y * Wk_s[tid];
            float zf = rz_s[128 + tid] + y * Wk_s[128 + tid];
            float zg = rz_s[256 + tid] + y * Wk_s[256 + tid];
            float zo = rz_s[384 + tid] + y * Wk_s[384 + tid];
            float si = rcpf_(1.f + ex2_(-L2E * zi));
            float sf = rcpf_(1.f + ex2_(-L2E * zf));
            float so = rcpf_(1.f + ex2_(-L2E * zo));
            float tg_ = 1.f - 2.f * rcpf_(ex2_(C2f * zg) + 1.f);
            float cn = sf * hc_s[128 + tid] + si * tg_;
            float tc = 1.f - 2.f * rcpf_(ex2_(C2f * cn) + 1.f);
            hc_s[128 + tid] = cn;
            hc_s[tid] = so * tc;
        }
        __syncthreads();
    }

    // ---- epilogue 1: one-shot ctx from final p (f32 enc, all 512 t)
    float* escr = (float*)pool_;     // Plds is dead; reuse as scratch
    {
        int eq = tid & 31, tg = tid >> 5;      // 32 groups x 16 rows
        float4 acc = make_float4(0.f,0.f,0.f,0.f);
        const float4* ep = (const float4*)(enc + ((size_t)b*T_ + tg*16)*E_) + eq;
        #pragma unroll
        for (int i = 0; i < 16; i++){
            float w = sc[tg*16 + i];
            float4 ev = ep[(size_t)i * 32];
            acc.x = fmaf(w, ev.x, acc.x); acc.y = fmaf(w, ev.y, acc.y);
            acc.z = fmaf(w, ev.z, acc.z); acc.w = fmaf(w, ev.w, acc.w);
        }
        *(float4*)(escr + tg*128 + eq*4) = acc;
    }
    __syncthreads();
    if (tid < 128){
        float s = 0.f;
        #pragma unroll
        for (int g2 = 0; g2 < 32; g2++) s += escr[g2*128 + tid];
        float dn = red[0]+red[1]+red[2]+red[3]+red[4]+red[5]+red[6]+red[7];
        ctx_s[tid] = s * rcpf_(dn);
    }
    __syncthreads();

    // ---- epilogue 2: pred = ([h, ctx] @ W1 + b1) @ W2 + b2   (h_==0 writes)
    if (tid < 128){
        float acc = b1[tid];
        for (int k = 0; k < 128; k++) acc = fmaf(hc_s[k],  W1[k*128 + tid], acc);
        for (int k = 0; k < 128; k++) acc = fmaf(ctx_s[k], W1[(128+k)*128 + tid], acc);
        escr[tid] = acc * W2[tid];
    }
    __syncthreads();
    if (h_ == 0 && tid < 64){
        float a = escr[tid] + escr[64 + tid];
        #pragma unroll
        for (int off = 32; off; off >>= 1) a += __shfl_xor(a, off);
        if (tid == 0) out[b] = a + b2[0];
    }
}

extern "C" void kernel_launch(void* const* d_in, const int* in_sizes, int n_in,
                              void* d_out, int out_size, void* d_ws, size_t ws_size,
                              hipStream_t stream){
    const float* enc      = (const float*)d_in[0];
    const float* labels   = (const float*)d_in[1];
    const float* init_h   = (const float*)d_in[2];
    const float* init_c   = (const float*)d_in[3];
    const float* Wa = (const float*)d_in[5];
    const float* ba = (const float*)d_in[6];
    const float* Ua = (const float*)d_in[7];
    const float* bu = (const float*)d_in[8];
    const float* Va = (const float*)d_in[9];
    // d_in[10] = bv: softmax-shift-invariant, unused
    const float* Wc = (const float*)d_in[11];
    const float* bc = (const float*)d_in[12];
    const float* Wk = (const float*)d_in[13];
    const float* Wr = (const float*)d_in[14];
    const float* bl = (const float*)d_in[15];
    const float* W1 = (const float*)d_in[16];
    const float* b1 = (const float*)d_in[17];
    const float* W2 = (const float*)d_in[18];
    const float* b2 = (const float*)d_in[19];

    char* ws = (char*)d_ws;
    const size_t szP = (size_t)B_ * T_ * T_ * 2;       // 67,108,864
    const size_t szWa = 512 * 256 * 2;                 // 262,144
    const size_t szWr = 512 * 128 * 2;                 // 131,072
    const size_t szG  = (size_t)B_ * T_ * 4;           // 262,144

    __half* P    = (__half*)ws;
    __half* Wa_t = (__half*)(ws + szP);
    __half* Wr_t = (__half*)(ws + szP + szWa);
    float*  gbuf = (float*)(ws + szP + szWa + szWr);
    float* psbuf = (float*)(ws + szP + szWa + szWr + szG);
    int*   flags = (int*)(psbuf + 2*256*768);
    int* fA = flags;           // [128][2]
    int* fB = flags + 256;     // [128][2]

    hipMemsetAsync(flags, 0, 512 * sizeof(int), stream);

    transpose_half<<<dim3(16, 8, 1), 256, 0, stream>>>(Wa, Wa_t, 256, 512);
    transpose_half<<<dim3(16, 4, 1), 256, 0, stream>>>(Wr, Wr_t, 128, 512);
    g_kernel<<<B_, 512, 0, stream>>>(enc, Wc, gbuf);

    dim3 g1(T_/64, T_/64, B_);
    uenc_kernel<<<g1, 256, 0, stream>>>(enc, Ua, bu, P);

    decoder_kernel<<<dim3(B_, 2), 1024, 0, stream>>>(enc,
        labels, init_h, init_c, Va, ba, bl, Wc, bc, Wk, W1, b1, W2, b2,
        Wa_t, Wr_t, P, gbuf, psbuf, fA, fB, (float*)d_out);
}

// Round 10
// 7501.419 us; speedup vs baseline: 2.0843x; 2.0843x over previous
//
#include <hip/hip_runtime.h>
#include <hip/hip_fp16.h>

#define B_ 128
#define T_ 512
#define E_ 128
#define D_ 128

// exp2(C2*x) == e^(2x);  L2E = log2(e)
#define C2f 2.885390081777927f
#define L2E 1.4426950408889634f

__device__ __forceinline__ float rcpf_(float x){ return __builtin_amdgcn_rcpf(x); }
__device__ __forceinline__ float ex2_(float x){ return __builtin_amdgcn_exp2f(x); }

// device-scope (cross-XCD coherent) data/flag helpers
__device__ __forceinline__ void gstoref(float* p, float v){
    __hip_atomic_store(p, v, __ATOMIC_RELAXED, __HIP_MEMORY_SCOPE_AGENT);
}
__device__ __forceinline__ float gloadf(const float* p){
    return __hip_atomic_load(p, __ATOMIC_RELAXED, __HIP_MEMORY_SCOPE_AGENT);
}
__device__ __forceinline__ void flag_set(int* p, int v){
    __hip_atomic_store(p, v, __ATOMIC_RELEASE, __HIP_MEMORY_SCOPE_AGENT);
}
__device__ __forceinline__ void flag_wait(int* p, int v){
    int it = 0;
    while (__hip_atomic_load(p, __ATOMIC_ACQUIRE, __HIP_MEMORY_SCOPE_AGENT) < v
           && it < (1 << 26)){ it++; __builtin_amdgcn_s_sleep(2); }
}

// out[n][k] = (half) in[k][n],  K x N input, 32x32 tiles, 256 threads.
__global__ __launch_bounds__(256) void transpose_half(const float* __restrict__ in,
                                                      __half* __restrict__ out,
                                                      int K, int N){
    __shared__ float tile[32][33];
    int n0 = blockIdx.x * 32, k0 = blockIdx.y * 32;
    int tx = threadIdx.x & 31, ty = threadIdx.x >> 5;
    #pragma unroll
    for (int i = ty; i < 32; i += 8)
        tile[i][tx] = in[(size_t)(k0 + i) * N + n0 + tx];
    __syncthreads();
    #pragma unroll
    for (int i = ty; i < 32; i += 8)
        out[(size_t)(n0 + i) * K + k0 + tx] = __float2half(tile[tx][i]);
}

// g[b][t] = sum_e enc[b][t][e] * Wc[1+e]   (fp32, loop-invariant y-dot basis)
__global__ __launch_bounds__(512) void g_kernel(const float* __restrict__ enc,
                                                const float* __restrict__ Wc,
                                                float* __restrict__ g){
    int b = blockIdx.x, t = threadIdx.x;
    const float4* ep = (const float4*)(enc + ((size_t)b * T_ + t) * E_);
    float acc = 0.f;
    #pragma unroll
    for (int i = 0; i < 32; i++){
        float4 ev = ep[i];
        acc = fmaf(ev.x, Wc[1 + 4*i + 0], acc);
        acc = fmaf(ev.y, Wc[1 + 4*i + 1], acc);
        acc = fmaf(ev.z, Wc[1 + 4*i + 2], acc);
        acc = fmaf(ev.w, Wc[1 + 4*i + 3], acc);
    }
    g[(size_t)b * T_ + t] = acc;
}

// P[b][n][t] = exp2(C2 * (sum_e enc[b][t][e]*Ua[e][n] + bu[n]))  as fp16
__global__ __launch_bounds__(256) void uenc_kernel(const float* __restrict__ enc,
                                                   const float* __restrict__ Ua,
                                                   const float* __restrict__ bu,
                                                   __half* __restrict__ P){
    int b = blockIdx.z;
    int t0 = blockIdx.x * 64;
    int n0 = blockIdx.y * 64;
    int tt = threadIdx.x & 63;
    int ng = threadIdx.x >> 6;
    const float* erow = enc + ((size_t)b * T_ + (t0 + tt)) * E_;
    const float* uap  = Ua + n0 + ng * 16;
    float acc[16];
    #pragma unroll
    for (int i = 0; i < 16; i++) acc[i] = 0.f;
    #pragma unroll 2
    for (int e0 = 0; e0 < E_; e0 += 4){
        float4 av = *(const float4*)(erow + e0);
        #pragma unroll
        for (int ee = 0; ee < 4; ee++){
            float a = (ee==0)?av.x:(ee==1)?av.y:(ee==2)?av.z:av.w;
            const float4* u4 = (const float4*)(uap + (size_t)(e0+ee) * T_);
            float4 x0 = u4[0], x1 = u4[1], x2 = u4[2], x3 = u4[3];
            acc[0]  = fmaf(a, x0.x, acc[0]);  acc[1]  = fmaf(a, x0.y, acc[1]);
            acc[2]  = fmaf(a, x0.z, acc[2]);  acc[3]  = fmaf(a, x0.w, acc[3]);
            acc[4]  = fmaf(a, x1.x, acc[4]);  acc[5]  = fmaf(a, x1.y, acc[5]);
            acc[6]  = fmaf(a, x1.z, acc[6]);  acc[7]  = fmaf(a, x1.w, acc[7]);
            acc[8]  = fmaf(a, x2.x, acc[8]);  acc[9]  = fmaf(a, x2.y, acc[9]);
            acc[10] = fmaf(a, x2.z, acc[10]); acc[11] = fmaf(a, x2.w, acc[11]);
            acc[12] = fmaf(a, x3.x, acc[12]); acc[13] = fmaf(a, x3.y, acc[13]);
            acc[14] = fmaf(a, x3.z, acc[14]); acc[15] = fmaf(a, x3.w, acc[15]);
        }
    }
    int nb = n0 + ng * 16;
    #pragma unroll
    for (int i = 0; i < 16; i++){
        float u = acc[i] + bu[nb + i];
        P[(size_t)b * T_ * T_ + (size_t)(nb + i) * T_ + t0 + tt] = __float2half(ex2_(C2f * u));
    }
}

__device__ __forceinline__ void dot8(float& acc, uint4 wv, float4 ha, float4 hb){
    float2 f0 = __half22float2(*reinterpret_cast<__half2*>(&wv.x));
    float2 f1 = __half22float2(*reinterpret_cast<__half2*>(&wv.y));
    float2 f2 = __half22float2(*reinterpret_cast<__half2*>(&wv.z));
    float2 f3 = __half22float2(*reinterpret_cast<__half2*>(&wv.w));
    acc = fmaf(ha.x, f0.x, acc); acc = fmaf(ha.y, f0.y, acc);
    acc = fmaf(ha.z, f1.x, acc); acc = fmaf(ha.w, f1.y, acc);
    acc = fmaf(hb.x, f2.x, acc); acc = fmaf(hb.y, f2.y, acc);
    acc = fmaf(hb.z, f3.x, acc); acc = fmaf(hb.w, f3.y, acc);
}

// 8 score-terms for one n-row: a_k += (-2Va[n]) / (P[n][t_k]*Q[n] + 1)
__device__ __forceinline__ void acc8(uint4 pv, float2 qv,
    float& a0, float& a1, float& a2, float& a3,
    float& a4, float& a5, float& a6, float& a7)
{
    float2 f0 = __half22float2(*reinterpret_cast<__half2*>(&pv.x));
    float2 f1 = __half22float2(*reinterpret_cast<__half2*>(&pv.y));
    float2 f2 = __half22float2(*reinterpret_cast<__half2*>(&pv.z));
    float2 f3 = __half22float2(*reinterpret_cast<__half2*>(&pv.w));
    float m;
    m = fmaf(f0.x, qv.x, 1.f); a0 = fmaf(rcpf_(m), qv.y, a0);
    m = fmaf(f0.y, qv.x, 1.f); a1 = fmaf(rcpf_(m), qv.y, a1);
    m = fmaf(f1.x, qv.x, 1.f); a2 = fmaf(rcpf_(m), qv.y, a2);
    m = fmaf(f1.y, qv.x, 1.f); a3 = fmaf(rcpf_(m), qv.y, a3);
    m = fmaf(f2.x, qv.x, 1.f); a4 = fmaf(rcpf_(m), qv.y, a4);
    m = fmaf(f2.y, qv.x, 1.f); a5 = fmaf(rcpf_(m), qv.y, a5);
    m = fmaf(f3.x, qv.x, 1.f); a6 = fmaf(rcpf_(m), qv.y, a6);
    m = fmaf(f3.y, qv.x, 1.f); a7 = fmaf(rcpf_(m), qv.y, a7);
}

// grid (128, 2): b = blockIdx.x, half-id h = blockIdx.y. 1024 threads.
// EXACT round-7 verified structure with ONE change: the second (pure-pacing)
// rendezvous is deleted. Correctness: partner's fA@t+1 set (at its B-final)
// strictly follows its p-phase@t read of the parity-t slot, and my next write
// to that slot is at step t+2 after passing fA@t+1 -> no overwrite race.
// Saves 2 __syncthreads + 1 cross-XCD round trip per step.
// (Round-9 lesson: L2-miss traffic is NOT the remaining bottleneck — stall
//  at sync points is. This is the minimal sync-reduction from the best run.)
__global__ __launch_bounds__(1024) void decoder_kernel(
    const float* __restrict__ enc,
    const float* __restrict__ labels,
    const float* __restrict__ init_h, const float* __restrict__ init_c,
    const float* __restrict__ Va,
    const float* __restrict__ ba, const float* __restrict__ bl,
    const float* __restrict__ Wc, const float* __restrict__ bc,
    const float* __restrict__ Wk,
    const float* __restrict__ W1, const float* __restrict__ b1,
    const float* __restrict__ W2, const float* __restrict__ b2,
    const __half* __restrict__ Wa_t, const __half* __restrict__ Wr_t,
    const __half* __restrict__ Pw, const float* __restrict__ gbuf,
    float* __restrict__ psbuf, int* __restrict__ fA,
    float* __restrict__ out)
{
    __shared__ __align__(16) __half Plds[128 * 512]; // 128 KB: LDS-resident P rows
    __shared__ __align__(16) float hc_s[256];        // h [0,128), c [128,256)
    __shared__ __align__(16) float ctx_s[128];
    __shared__ __align__(16) float Q_s[256];         // e^{2 s[n]}, own half (local n)
    __shared__ __align__(16) float Vam_s[256];       // -2*Va[n], own half
    __shared__ __align__(16) float sc[512];          // half-score -> p[t]
    __shared__ __align__(16) float rz_s[512];        // h@Wr + bl (global m index)
    __shared__ __align__(16) float g_s[512];         // g[b][t]
    __shared__ __align__(16) float scratch[4096];    // 16 KB partials
    __shared__ __align__(16) float ba_s[256], bl_s[256];
    __shared__ __align__(16) float Wk_s[512];
    __shared__ float Wc_s[132];
    __shared__ float red[20];                        // 0-7 denom, 8-15 p.g

    const int tid = threadIdx.x;
    const int b = blockIdx.x;
    const int h_ = blockIdx.y;          // n-half / m-half id
    const int par_stride = B_ * 2;      // pair-slot layout

    if (tid < 128){
        hc_s[tid]       = init_h[b*128 + tid];
        hc_s[128 + tid] = init_c[b*128 + tid];
    }
    if (tid < 256){
        Vam_s[tid] = -2.f * Va[256*h_ + tid];
        ba_s[tid]  = ba[256*h_ + tid];
        bl_s[tid]  = bl[256*h_ + tid];
    }
    if (tid < 512){
        Wk_s[tid] = Wk[tid];
        g_s[tid]  = gbuf[(size_t)b * T_ + tid];
    }
    if (tid < 129) Wc_s[tid] = Wc[tid];
    if (tid == 129) Wc_s[130] = bc[0];

    // block's n-half of P: rows n_loc in [0,256), global n = 256*h_ + n_loc
    const __half* Pb  = Pw + ((size_t)b * T_ + 256 * h_) * T_;
    const uint4*  Pb4 = (const uint4*)Pb;

    // Fill LDS rows: n_loc = 16g + j for j<8  ->  lds row r = 8g + j
    {
        int wid = tid >> 6, lane = tid & 63;
        for (int r = wid; r < 128; r += 16){
            int g = r >> 3, j = r & 7;
            *((uint4*)Plds + (size_t)r * 64 + lane) =
                Pb4[(size_t)(16*g + j) * 64 + lane];
        }
    }
    __syncthreads();

    int* myfA = &fA[b*2 + h_];   int* pfA = &fA[b*2 + (1 - h_)];

    const int np_ = tid & 255;   // phase-A row (local n or local m)
    const int kq_ = tid >> 8;    // phase-A k-quarter

    for (int t = 0; t < T_; t++){
        const int par = t & 1;
        float* psme = psbuf + ((size_t)par * par_stride + b*2 + h_)     * 768;
        float* pspr = psbuf + ((size_t)par * par_stride + b*2 + (1-h_)) * 768;

        // ---- phase A: s[n] own n-half (k/4) ; rz[m] own m-half (k/4)
        {
            const float4* hc4 = (const float4*)hc_s;
            {   // s: 8 uint4 of Wa_t row (k in [kq_*64, kq_*64+64))
                float acc = (kq_ == 0) ? ba_s[np_] : 0.f;
                const uint4* wa = (const uint4*)(Wa_t + (size_t)(256*h_ + np_) * 256 + kq_ * 64);
                #pragma unroll 4
                for (int i = 0; i < 8; i++){
                    uint4 wv = wa[i];
                    dot8(acc, wv, hc4[kq_*16 + 2*i], hc4[kq_*16 + 2*i + 1]);
                }
                scratch[kq_*256 + np_] = acc;
            }
            {   // rz: 4 uint4 of Wr_t row (k in [kq_*32, kq_*32+32))
                float accr = (kq_ == 0) ? bl_s[np_] : 0.f;
                const uint4* wr = (const uint4*)(Wr_t + (size_t)(256*h_ + np_) * 128 + kq_ * 32);
                #pragma unroll
                for (int i = 0; i < 4; i++){
                    uint4 wv = wr[i];
                    dot8(accr, wv, hc4[kq_*8 + 2*i], hc4[kq_*8 + 2*i + 1]);
                }
                scratch[1024 + kq_*256 + np_] = accr;
            }
        }
        __syncthreads();
        if (tid < 256){
            float s = scratch[tid] + scratch[256+tid] + scratch[512+tid] + scratch[768+tid];
            Q_s[tid] = ex2_(C2f * s);
        } else if (tid < 512){
            int m = tid - 256;
            float rzv = scratch[1024+m] + scratch[1280+m] + scratch[1536+m] + scratch[1792+m];
            rz_s[256*h_ + m] = rzv;
            gstoref(&psme[512 + m], rzv);   // publish own rz-half (covered by flagA release)
        }
        __syncthreads();

        // ---- phase B: half-score over own 256 n-rows; 8 LDS + 8 global rows/group
        float a0=0.f,a1=0.f,a2=0.f,a3=0.f,a4=0.f,a5=0.f,a6=0.f,a7=0.f;
        {
            int q = tid & 63, g = tid >> 6;
            const uint4* Pl = (const uint4*)Plds + (size_t)(8*g) * 64 + q;
            #pragma unroll
            for (int j = 0; j < 8; j++){
                uint4 pv = Pl[j * 64];
                float2 qv = make_float2(Q_s[16*g + j], Vam_s[16*g + j]);
                acc8(pv, qv, a0,a1,a2,a3,a4,a5,a6,a7);
            }
            const uint4* Pg = Pb4 + (size_t)(16*g + 8) * 64 + q;
            #pragma unroll 4
            for (int j = 0; j < 8; j++){
                uint4 pv = Pg[(size_t)j * 64];
                float2 qv = make_float2(Q_s[16*g + 8 + j], Vam_s[16*g + 8 + j]);
                acc8(pv, qv, a0,a1,a2,a3,a4,a5,a6,a7);
            }
        }
        // ---- 3-stage in-place B-reduce (scratch = 8 x 512 floats)
        {
            int q = tid & 63, g = tid >> 6;
            float4* o = (float4*)(scratch + (g & 7)*512 + q*8);
            if (g >= 8){
                o[0] = make_float4(a0,a1,a2,a3);
                o[1] = make_float4(a4,a5,a6,a7);
            }
            __syncthreads();
            if (g < 8){
                float4 p0 = o[0], p1 = o[1];
                o[0] = make_float4(a0+p0.x, a1+p0.y, a2+p0.z, a3+p0.w);
                o[1] = make_float4(a4+p1.x, a5+p1.y, a6+p1.z, a7+p1.w);
            }
        }
        __syncthreads();
        // ---- final B-reduce -> half-score; publish to partner
        if (tid < 512){
            float v = 0.f;
            #pragma unroll
            for (int g = 0; g < 8; g++) v += scratch[g*512 + tid];
            sc[tid] = v;
            gstoref(&psme[tid], v);
        }
        __syncthreads();
        if (tid == 0){ flag_set(myfA, t + 1); flag_wait(pfA, t + 1); }
        __syncthreads();
        // ---- full score -> p; denom + p.g partials; pull partner rz-half
        if (tid < 512){
            float score = sc[tid] + gloadf(&pspr[tid]);
            float p = ex2_(score * L2E);
            sc[tid] = p;
            float ss = p;
            float sg = p * g_s[tid];
            #pragma unroll
            for (int off = 32; off; off >>= 1){
                ss += __shfl_xor(ss, off);
                sg += __shfl_xor(sg, off);
            }
            if ((tid & 63) == 0){ red[tid >> 6] = ss; red[8 + (tid >> 6)] = sg; }
        } else if (tid < 768){
            int m = tid - 512;
            rz_s[256*(1-h_) + m] = gloadf(&pspr[512 + m]);
        }
        __syncthreads();

        // ---- phase D: y from (p.g)/denom; gates (Keras i,f,g,o); update h,c
        if (tid < 128){
            float dn = red[0]+red[1]+red[2]+red[3]+red[4]+red[5]+red[6]+red[7];
            float pg = red[8]+red[9]+red[10]+red[11]+red[12]+red[13]+red[14]+red[15];
            float lab = labels[(size_t)b * T_ + t];
            float y = fmaf(lab, Wc_s[0], pg * rcpf_(dn) + Wc_s[130]);
            float zi = rz_s[tid]       + y * Wk_s[tid];
            float zf = rz_s[128 + tid] + y * Wk_s[128 + tid];
            float zg = rz_s[256 + tid] + y * Wk_s[256 + tid];
            float zo = rz_s[384 + tid] + y * Wk_s[384 + tid];
            float si = rcpf_(1.f + ex2_(-L2E * zi));
            float sf = rcpf_(1.f + ex2_(-L2E * zf));
            float so = rcpf_(1.f + ex2_(-L2E * zo));
            float tg_ = 1.f - 2.f * rcpf_(ex2_(C2f * zg) + 1.f);
            float cn = sf * hc_s[128 + tid] + si * tg_;
            float tc = 1.f - 2.f * rcpf_(ex2_(C2f * cn) + 1.f);
            hc_s[128 + tid] = cn;
            hc_s[tid] = so * tc;
        }
        __syncthreads();
    }

    // ---- epilogue 1: one-shot ctx from final p (f32 enc, all 512 t)
    {
        int eq = tid & 31, tg = tid >> 5;      // 32 groups x 16 rows
        float4 acc = make_float4(0.f,0.f,0.f,0.f);
        const float4* ep = (const float4*)(enc + ((size_t)b*T_ + tg*16)*E_) + eq;
        #pragma unroll
        for (int i = 0; i < 16; i++){
            float w = sc[tg*16 + i];
            float4 ev = ep[(size_t)i * 32];
            acc.x = fmaf(w, ev.x, acc.x); acc.y = fmaf(w, ev.y, acc.y);
            acc.z = fmaf(w, ev.z, acc.z); acc.w = fmaf(w, ev.w, acc.w);
        }
        *(float4*)(scratch + tg*128 + eq*4) = acc;
    }
    __syncthreads();
    if (tid < 128){
        float s = 0.f;
        #pragma unroll
        for (int g2 = 0; g2 < 32; g2++) s += scratch[g2*128 + tid];
        float dn = red[0]+red[1]+red[2]+red[3]+red[4]+red[5]+red[6]+red[7];
        ctx_s[tid] = s * rcpf_(dn);
    }
    __syncthreads();

    // ---- epilogue 2: pred = ([h, ctx] @ W1 + b1) @ W2 + b2   (h_==0 writes)
    if (tid < 128){
        float acc = b1[tid];
        for (int k = 0; k < 128; k++) acc = fmaf(hc_s[k],  W1[k*128 + tid], acc);
        for (int k = 0; k < 128; k++) acc = fmaf(ctx_s[k], W1[(128+k)*128 + tid], acc);
        scratch[tid] = acc * W2[tid];
    }
    __syncthreads();
    if (h_ == 0 && tid < 64){
        float a = scratch[tid] + scratch[64 + tid];
        #pragma unroll
        for (int off = 32; off; off >>= 1) a += __shfl_xor(a, off);
        if (tid == 0) out[b] = a + b2[0];
    }
}

extern "C" void kernel_launch(void* const* d_in, const int* in_sizes, int n_in,
                              void* d_out, int out_size, void* d_ws, size_t ws_size,
                              hipStream_t stream){
    const float* enc      = (const float*)d_in[0];
    const float* labels   = (const float*)d_in[1];
    const float* init_h   = (const float*)d_in[2];
    const float* init_c   = (const float*)d_in[3];
    const float* Wa = (const float*)d_in[5];
    const float* ba = (const float*)d_in[6];
    const float* Ua = (const float*)d_in[7];
    const float* bu = (const float*)d_in[8];
    const float* Va = (const float*)d_in[9];
    // d_in[10] = bv: softmax-shift-invariant, unused
    const float* Wc = (const float*)d_in[11];
    const float* bc = (const float*)d_in[12];
    const float* Wk = (const float*)d_in[13];
    const float* Wr = (const float*)d_in[14];
    const float* bl = (const float*)d_in[15];
    const float* W1 = (const float*)d_in[16];
    const float* b1 = (const float*)d_in[17];
    const float* W2 = (const float*)d_in[18];
    const float* b2 = (const float*)d_in[19];

    char* ws = (char*)d_ws;
    const size_t szP = (size_t)B_ * T_ * T_ * 2;       // 67,108,864
    const size_t szWa = 512 * 256 * 2;                 // 262,144
    const size_t szWr = 512 * 128 * 2;                 // 131,072
    const size_t szG  = (size_t)B_ * T_ * 4;           // 262,144

    __half* P    = (__half*)ws;
    __half* Wa_t = (__half*)(ws + szP);
    __half* Wr_t = (__half*)(ws + szP + szWa);
    float*  gbuf = (float*)(ws + szP + szWa + szWr);
    float* psbuf = (float*)(ws + szP + szWa + szWr + szG);
    int*   flags = (int*)(psbuf + 2*256*768);

    hipMemsetAsync(flags, 0, 512 * sizeof(int), stream);

    transpose_half<<<dim3(16, 8, 1), 256, 0, stream>>>(Wa, Wa_t, 256, 512);
    transpose_half<<<dim3(16, 4, 1), 256, 0, stream>>>(Wr, Wr_t, 128, 512);
    g_kernel<<<B_, 512, 0, stream>>>(enc, Wc, gbuf);

    dim3 g1(T_/64, T_/64, B_);
    uenc_kernel<<<g1, 256, 0, stream>>>(enc, Ua, bu, P);

    decoder_kernel<<<dim3(B_, 2), 1024, 0, stream>>>(enc,
        labels, init_h, init_c, Va, ba, bl, Wc, bc, Wk, W1, b1, W2, b2,
        Wa_t, Wr_t, P, gbuf, psbuf, flags, (float*)d_out);
}